// Round 3
// baseline (180.406 us; speedup 1.0000x reference)
//
#include <hip/hip_runtime.h>

// WordSAGE on MI355X — fp32 in/out. Round-13 structure (2 kernels + memset):
//   k_prep : [edge fillpad x8/thread | gene->GH | weight pack]. No AF.
//   k_mega : 16 rows/block, 1250 blocks, 512 thr (8 waves) -> ~32 waves/CU
//            resident (was 13 at 32 rows/625 blocks; grid-limited occupancy
//            was the round-12 bottleneck — gather is L2-latency-bound).
//            phase0 = {issue train loads -> gather-mean (32 thr/row, uint2)
//            -> stage train tile bf16 in LDS (overlay S1/S2)}, then fused
//            4-layer split-bf16 MFMA; wave = col-group, 1 acc chain.
// Precision: weights/agg/h split hi+lo bf16; train & gene hi-only (RNE).

#define NG 2500
#define NT 20000
#define NE 640000
#define NCLS 16
#define CAP 96

typedef unsigned short u16;
typedef unsigned int u32;

typedef float f32x4 __attribute__((ext_vector_type(4)));
typedef __bf16 bf16x8 __attribute__((ext_vector_type(8)));

__device__ __forceinline__ float b2f(u16 u) { return __uint_as_float(((u32)u) << 16); }
__device__ __forceinline__ float blo(u32 p) { return __uint_as_float(p << 16); }
__device__ __forceinline__ float bhi(u32 p) { return __uint_as_float(p & 0xffff0000u); }
__device__ __forceinline__ u16 f2b(float f) {  // RNE fp32->bf16
    u32 u = __float_as_uint(f);
    return (u16)((u + 0x7fffu + ((u >> 16) & 1u)) >> 16);
}

// ---- sizes ---------------------------------------------------------------
#define B1N 81920   // K=640: train k 0..499, zero 500..511, agg 512..639; N=128
#define B2N 32768   // K=256: h1 (W2s) 0..127, agg (W2n) 128..255; N=128
#define B3N 16384   // K=128 Wc1, N=128
#define B4N 2048    // K=128 Wc2, N=16
#define NEB 313     // edge blocks (8 edges/thread)
#define GNB 625     // gene-convert blocks
#define PKB 520     // pack blocks

// ---- fused prep -----------------------------------------------------------
__global__ __launch_bounds__(256) void k_prep(
    const int* __restrict__ esrc, const int* __restrict__ edst,
    int* __restrict__ cnt, u16* __restrict__ csr,
    const float* __restrict__ gene, u32* __restrict__ GH32,
    const float* __restrict__ W1n, const float* __restrict__ W1s,
    const float* __restrict__ W2n, const float* __restrict__ W2s,
    const float* __restrict__ Wc1, const float* __restrict__ Wc2,
    u16* __restrict__ B1h, u16* __restrict__ B1l,
    u16* __restrict__ B2h, u16* __restrict__ B2l,
    u16* __restrict__ B3h, u16* __restrict__ B3l,
    u16* __restrict__ B4h, u16* __restrict__ B4l) {
    int blk = blockIdx.x, t = threadIdx.x;
    if (blk < NEB) {
        int e0 = (blk * 256 + t) * 8;
        if (e0 < NE) {                      // NE % 8 == 0 -> all-or-nothing
            int4 sA = *(const int4*)(esrc + e0);
            int4 sB = *(const int4*)(esrc + e0 + 4);
            int4 dA = *(const int4*)(edst + e0);
            int4 dB = *(const int4*)(edst + e0 + 4);
            int ss[8] = {sA.x, sA.y, sA.z, sA.w, sB.x, sB.y, sB.z, sB.w};
            int dd[8] = {dA.x, dA.y, dA.z, dA.w, dB.x, dB.y, dB.z, dB.w};
#pragma unroll
            for (int i = 0; i < 8; ++i) {   // 8 independent atomic chains
                unsigned d = (unsigned)dd[i];
                if (d < NT) {
                    int slot = atomicAdd(&cnt[d], 1);
                    if (slot < CAP) csr[(size_t)d * CAP + slot] = (u16)ss[i];
                }
            }
        }
        return;
    }
    if (blk < NEB + GNB) {
        int idx = (blk - NEB) * 256 + t;  // < 160000
        float2 v = ((const float2*)gene)[idx];
        GH32[idx] = (u32)f2b(v.x) | ((u32)f2b(v.y) << 16);
        return;
    }
    // ---- weight pack (split hi/lo, B-fragment order) ----
    int idx = (blk - NEB - GNB) * 256 + t;
    float v = 0.f;
    u16 *ph = 0, *pl = 0;
    int off = 0;
    if (idx < B1N) {
        int j = idx & 7, l = (idx >> 3) & 63, rest = idx >> 9;
        int g = rest & 7, kk = rest >> 3;
        int k = kk * 32 + ((l >> 4) << 3) + j, n = (g << 4) + (l & 15);
        if (k < 500) v = W1s[k * 128 + n];
        else if (k >= 512) v = W1n[(k - 512) * 128 + n];
        ph = B1h; pl = B1l; off = idx;
    } else if (idx < B1N + B2N) {
        int e = idx - B1N;
        int j = e & 7, l = (e >> 3) & 63, rest = e >> 9;
        int g = rest & 7, kk = rest >> 3;
        int k = kk * 32 + ((l >> 4) << 3) + j, n = (g << 4) + (l & 15);
        v = (k < 128) ? W2s[k * 128 + n] : W2n[(k - 128) * 128 + n];
        ph = B2h; pl = B2l; off = e;
    } else if (idx < B1N + B2N + B3N) {
        int e = idx - (B1N + B2N);
        int j = e & 7, l = (e >> 3) & 63, rest = e >> 9;
        int g = rest & 7, kk = rest >> 3;
        int k = kk * 32 + ((l >> 4) << 3) + j, n = (g << 4) + (l & 15);
        v = Wc1[k * 128 + n];
        ph = B3h; pl = B3l; off = e;
    } else if (idx < B1N + B2N + B3N + B4N) {
        int e = idx - (B1N + B2N + B3N);
        int j = e & 7, l = (e >> 3) & 63, kk = e >> 9;
        int k = kk * 32 + ((l >> 4) << 3) + j, n = l & 15;
        v = Wc2[k * 16 + n];
        ph = B4h; pl = B4l; off = e;
    }
    if (ph) {
        u16 hi = f2b(v);
        u16 lo = f2b(v - b2f(hi));
        ph[off] = hi;
        pl[off] = lo;
    }
}

// ---- fused gather + stage + 4-layer MFMA ----------------------------------
// Block: 512 thr (8 waves), 16 rows (1 tile). wave = col-group g (0..7),
// single acc chain. Shared pool (u16 units):
//   SAGh @0     [16*136]   SAGl @2176  [16*136]
//   S1h  @4352  [16*136]   S1l  @6528  [16*136]
//   S2h  @8704  [16*136]   S2l  @10880 [16*136]
//   TS   @4352  [16*520]  (train tile bf16, overlays S1h..S2l; dead after
//                          layer1 kk0..15 -> barrier before S1 epilogue)
__global__ __launch_bounds__(512) void k_mega(
    const int* __restrict__ cnt, const u16* __restrict__ csr,
    const u16* __restrict__ GH, const float* __restrict__ train,
    const u16* __restrict__ B1h, const u16* __restrict__ B1l,
    const u16* __restrict__ B2h, const u16* __restrict__ B2l,
    const u16* __restrict__ B3h, const u16* __restrict__ B3l,
    const u16* __restrict__ B4h, const u16* __restrict__ B4l,
    const float* __restrict__ b1, const float* __restrict__ b2,
    const float* __restrict__ bc1, const float* __restrict__ bc2,
    float* __restrict__ out) {
    __shared__ __align__(16) u16 SMEM[13056];   // 26112 B
    u16* SAGh = SMEM;
    u16* SAGl = SMEM + 2176;
    u16* S1h = SMEM + 4352;
    u16* S1l = SMEM + 6528;
    u16* S2h = SMEM + 8704;
    u16* S2l = SMEM + 10880;
    u16* TS = SMEM + 4352;                      // overlays S1h..S2l (8320 u16)

    int t = threadIdx.x;
    int row0 = blockIdx.x * 16;

    // ---- phase 0a: issue train-tile loads (latency hides under gather) ----
    // 16 rows x 125 float4 = 2000; threads 0..511 x {0,512,1024[,1536]}
    float4 st0, st1, st2, st3;
    {
        const float4* tb = (const float4*)(train + (size_t)row0 * 500);
        st0 = tb[t];
        st1 = tb[t + 512];
        st2 = tb[t + 1024];
        int i3 = (t < 464) ? (t + 1536) : 0;   // guard OOB, value unused if >=464
        st3 = tb[i3];
    }

    // ---- phase 0b: gather-mean of gene-hi into SAG (32 thr/row, uint2) ----
    {
        int r = t >> 5, cg = t & 31;           // row 0..15, col-group 0..31
        int d = row0 + r;
        int ctrue = cnt[d];
        int c = ctrue > CAP ? CAP : ctrue;
        const u16* crow = csr + (size_t)d * CAP;
        float a0 = 0.f, a1 = 0.f, a2 = 0.f, a3 = 0.f;
        int j = 0;
        for (; j + 1 < c; j += 2) {
            int s0 = crow[j], s1 = crow[j + 1];
            uint2 p0 = *(const uint2*)(GH + (size_t)s0 * 128 + cg * 4);
            uint2 p1 = *(const uint2*)(GH + (size_t)s1 * 128 + cg * 4);
            a0 += blo(p0.x); a1 += bhi(p0.x);
            a2 += blo(p0.y); a3 += bhi(p0.y);
            a0 += blo(p1.x); a1 += bhi(p1.x);
            a2 += blo(p1.y); a3 += bhi(p1.y);
        }
        if (j < c) {
            int s = crow[j];
            uint2 p0 = *(const uint2*)(GH + (size_t)s * 128 + cg * 4);
            a0 += blo(p0.x); a1 += bhi(p0.x);
            a2 += blo(p0.y); a3 += bhi(p0.y);
        }
        float inv = (ctrue > 0) ? 1.f / (float)ctrue : 0.f;
        int base = r * 68 + cg * 2;            // u32 index
        u32* SH = (u32*)SAGh;
        u32* SL = (u32*)SAGl;
        float x = a0 * inv, y = a1 * inv;
        u16 hx = f2b(x), hy = f2b(y);
        SH[base] = (u32)hx | ((u32)hy << 16);
        SL[base] = (u32)f2b(x - b2f(hx)) | ((u32)f2b(y - b2f(hy)) << 16);
        x = a2 * inv; y = a3 * inv;
        hx = f2b(x); hy = f2b(y);
        SH[base + 1] = (u32)hx | ((u32)hy << 16);
        SL[base + 1] = (u32)f2b(x - b2f(hx)) | ((u32)f2b(y - b2f(hy)) << 16);
    }

    // ---- phase 0c: convert staged tile -> TS (row-major [16][520] bf16) ----
    {
        u32* T32 = (u32*)TS;
        int idx = t;
        {
            int r = idx / 125, c4 = idx - r * 125;
            int base = r * 260 + c4 * 2;
            T32[base] = (u32)f2b(st0.x) | ((u32)f2b(st0.y) << 16);
            T32[base + 1] = (u32)f2b(st0.z) | ((u32)f2b(st0.w) << 16);
        }
        idx = t + 512;
        {
            int r = idx / 125, c4 = idx - r * 125;
            int base = r * 260 + c4 * 2;
            T32[base] = (u32)f2b(st1.x) | ((u32)f2b(st1.y) << 16);
            T32[base + 1] = (u32)f2b(st1.z) | ((u32)f2b(st1.w) << 16);
        }
        idx = t + 1024;
        {
            int r = idx / 125, c4 = idx - r * 125;
            int base = r * 260 + c4 * 2;
            T32[base] = (u32)f2b(st2.x) | ((u32)f2b(st2.y) << 16);
            T32[base + 1] = (u32)f2b(st2.z) | ((u32)f2b(st2.w) << 16);
        }
        if (t < 464) {
            idx = t + 1536;
            int r = idx / 125, c4 = idx - r * 125;
            int base = r * 260 + c4 * 2;
            T32[base] = (u32)f2b(st3.x) | ((u32)f2b(st3.y) << 16);
            T32[base + 1] = (u32)f2b(st3.z) | ((u32)f2b(st3.w) << 16);
        }
        if (t < 96) {                           // zero cols 500..511
            int r = t / 6, c = t - r * 6;
            T32[r * 260 + 250 + c] = 0;
        }
    }
    __syncthreads();

    int lane = t & 63, g = t >> 6;  // wave index = col-group 0..7
    int m = lane & 15, q = lane >> 4, n16 = lane & 15;

    int hr0 = m * 136 + q * 8;
    int cr0 = q * 4;
    const f32x4 z4 = {0.f, 0.f, 0.f, 0.f};
    f32x4 acc0 = z4;

    // ---- layer1: K=640 (train bf16 kk0..15 from TS; agg kk16..19 SAG) ----
    const u16* tA0 = TS + m * 520 + q * 8;
#pragma unroll
    for (int kk = 0; kk < 16; ++kk) {
        bf16x8 a0 = *(const bf16x8*)(tA0 + kk * 32);
        size_t bo = ((size_t)(kk * 8 + g) * 64 + lane) * 8;
        bf16x8 bh = *(const bf16x8*)(B1h + bo);
        bf16x8 bl = *(const bf16x8*)(B1l + bo);
        acc0 = __builtin_amdgcn_mfma_f32_16x16x32_bf16(a0, bh, acc0, 0, 0, 0);
        acc0 = __builtin_amdgcn_mfma_f32_16x16x32_bf16(a0, bl, acc0, 0, 0, 0);
    }
#pragma unroll
    for (int kk = 16; kk < 20; ++kk) {
        int o = (kk - 16) * 32;
        bf16x8 ah0 = *(const bf16x8*)(SAGh + hr0 + o);
        bf16x8 al0 = *(const bf16x8*)(SAGl + hr0 + o);
        size_t bo = ((size_t)(kk * 8 + g) * 64 + lane) * 8;
        bf16x8 bh = *(const bf16x8*)(B1h + bo);
        bf16x8 bl = *(const bf16x8*)(B1l + bo);
        acc0 = __builtin_amdgcn_mfma_f32_16x16x32_bf16(ah0, bh, acc0, 0, 0, 0);
        acc0 = __builtin_amdgcn_mfma_f32_16x16x32_bf16(ah0, bl, acc0, 0, 0, 0);
        acc0 = __builtin_amdgcn_mfma_f32_16x16x32_bf16(al0, bh, acc0, 0, 0, 0);
    }
    __syncthreads();   // TS (overlaid on S1/S2) dead only when ALL waves passed
    {
        int n = g * 16 + n16;
        float bias = b1[n];
#pragma unroll
        for (int rg = 0; rg < 4; ++rg) {
            float v0 = acc0[rg] + bias; v0 = v0 > 0.f ? v0 : 0.f;
            u16 h0 = f2b(v0);
            S1h[(cr0 + rg) * 136 + n] = h0;
            S1l[(cr0 + rg) * 136 + n] = f2b(v0 - b2f(h0));
        }
    }
    __syncthreads();

    // ---- layer2: K=256 (h1 kk0..3 S1; agg kk4..7 SAG) ----
    acc0 = z4;
#pragma unroll
    for (int kk = 0; kk < 8; ++kk) {
        const u16* Ph = (kk < 4) ? S1h : SAGh;
        const u16* Pl = (kk < 4) ? S1l : SAGl;
        int o = (kk & 3) * 32;
        bf16x8 ah0 = *(const bf16x8*)(Ph + hr0 + o);
        bf16x8 al0 = *(const bf16x8*)(Pl + hr0 + o);
        size_t bo = ((size_t)(kk * 8 + g) * 64 + lane) * 8;
        bf16x8 bh = *(const bf16x8*)(B2h + bo);
        bf16x8 bl = *(const bf16x8*)(B2l + bo);
        acc0 = __builtin_amdgcn_mfma_f32_16x16x32_bf16(ah0, bh, acc0, 0, 0, 0);
        acc0 = __builtin_amdgcn_mfma_f32_16x16x32_bf16(ah0, bl, acc0, 0, 0, 0);
        acc0 = __builtin_amdgcn_mfma_f32_16x16x32_bf16(al0, bh, acc0, 0, 0, 0);
    }
    {
        int n = g * 16 + n16;
        float bias = b2[n];
#pragma unroll
        for (int rg = 0; rg < 4; ++rg) {
            float v0 = acc0[rg] + bias; v0 = v0 > 0.f ? v0 : 0.f;
            u16 h0 = f2b(v0);
            S2h[(cr0 + rg) * 136 + n] = h0;
            S2l[(cr0 + rg) * 136 + n] = f2b(v0 - b2f(h0));
        }
    }
    __syncthreads();

    // ---- layer3: K=128 (h2 S2) -> S1 ----
    acc0 = z4;
#pragma unroll
    for (int kk = 0; kk < 4; ++kk) {
        int o = kk * 32;
        bf16x8 ah0 = *(const bf16x8*)(S2h + hr0 + o);
        bf16x8 al0 = *(const bf16x8*)(S2l + hr0 + o);
        size_t bo = ((size_t)(kk * 8 + g) * 64 + lane) * 8;
        bf16x8 bh = *(const bf16x8*)(B3h + bo);
        bf16x8 bl = *(const bf16x8*)(B3l + bo);
        acc0 = __builtin_amdgcn_mfma_f32_16x16x32_bf16(ah0, bh, acc0, 0, 0, 0);
        acc0 = __builtin_amdgcn_mfma_f32_16x16x32_bf16(ah0, bl, acc0, 0, 0, 0);
        acc0 = __builtin_amdgcn_mfma_f32_16x16x32_bf16(al0, bh, acc0, 0, 0, 0);
    }
    {
        int n = g * 16 + n16;
        float bias = bc1[n];
#pragma unroll
        for (int rg = 0; rg < 4; ++rg) {
            float v0 = acc0[rg] + bias; v0 = v0 > 0.f ? v0 : 0.f;
            u16 h0 = f2b(v0);
            S1h[(cr0 + rg) * 136 + n] = h0;
            S1l[(cr0 + rg) * 136 + n] = f2b(v0 - b2f(h0));
        }
    }
    __syncthreads();

    // ---- layer4: K=128, N=16 (wave 0) ----
    if (g == 0) {
        f32x4 a4 = z4;
#pragma unroll
        for (int kk = 0; kk < 4; ++kk) {
            bf16x8 ah = *(const bf16x8*)(S1h + hr0 + kk * 32);
            bf16x8 al = *(const bf16x8*)(S1l + hr0 + kk * 32);
            size_t bo = ((size_t)kk * 64 + lane) * 8;
            bf16x8 bh = *(const bf16x8*)(B4h + bo);
            bf16x8 bl = *(const bf16x8*)(B4l + bo);
            a4 = __builtin_amdgcn_mfma_f32_16x16x32_bf16(ah, bh, a4, 0, 0, 0);
            a4 = __builtin_amdgcn_mfma_f32_16x16x32_bf16(ah, bl, a4, 0, 0, 0);
            a4 = __builtin_amdgcn_mfma_f32_16x16x32_bf16(al, bh, a4, 0, 0, 0);
        }
        float bias = bc2[n16];
#pragma unroll
        for (int rg = 0; rg < 4; ++rg)
            out[(size_t)(row0 + cr0 + rg) * NCLS + n16] = a4[rg] + bias;
    }
}

extern "C" void kernel_launch(void* const* d_in, const int* in_sizes, int n_in,
                              void* d_out, int out_size, void* d_ws, size_t ws_size,
                              hipStream_t stream) {
    const float* gene = (const float*)d_in[0];
    const float* train = (const float*)d_in[1];
    const int* esrc = (const int*)d_in[2];
    const int* edst = (const int*)d_in[3];

    char* ws = (char*)d_ws;
    int* cnt = (int*)(ws + 0);              //    80000
    u16* csr = (u16*)(ws + 80000);          //  3840000
    u16* GH = (u16*)(ws + 3920000);         //   640000 (2500*128 u16)
    u16* B1h = (u16*)(ws + 4560000);        //   163840
    u16* B1l = (u16*)(ws + 4723840);        //   163840
    u16* B2h = (u16*)(ws + 4887680);        //    65536
    u16* B2l = (u16*)(ws + 4953216);        //    65536
    u16* B3h = (u16*)(ws + 5018752);        //    32768
    u16* B3l = (u16*)(ws + 5051520);        //    32768
    u16* B4h = (u16*)(ws + 5084288);        //     4096
    u16* B4l = (u16*)(ws + 5088384);        //     4096
    // total 5,092,480 B

    hipMemsetAsync(cnt, 0, NT * sizeof(int), stream);
    k_prep<<<NEB + GNB + PKB, 256, 0, stream>>>(
        esrc, edst, cnt, csr, gene, (u32*)GH,
        (const float*)d_in[4], (const float*)d_in[5], (const float*)d_in[7],
        (const float*)d_in[8], (const float*)d_in[10], (const float*)d_in[12],
        B1h, B1l, B2h, B2l, B3h, B3l, B4h, B4l);
    k_mega<<<NT / 16, 512, 0, stream>>>(
        cnt, csr, GH, train, B1h, B1l, B2h, B2l, B3h, B3l, B4h, B4l,
        (const float*)d_in[6], (const float*)d_in[9], (const float*)d_in[11],
        (const float*)d_in[13], (float*)d_out);
}

// Round 4
// 178.170 us; speedup vs baseline: 1.0125x; 1.0125x over previous
//
#include <hip/hip_runtime.h>

// WordSAGE on MI355X — fp32 in/out. Round-14 structure (2 kernels + memset):
//   k_prep : [edge fillpad x8/thread | gene->GH | weight pack]. No AF.
//   k_mega : ROUND-12 SHAPE (32 rows/block, 625 blocks, 8 waves; r13's
//            16-row split regressed: B L2-traffic doubled, occupancy wasn't
//            the limiter). NEW: gather loads 8 neighbor indices per uint4
//            (MLP 2 -> ~8 on the random GH row reads; the crow->GH serial
//            2-latency chain was the r12 bottleneck). Tail = one clamped
//            predicated batch; per-thread sum order unchanged (bit-identical).
// Precision: weights/agg/h split hi+lo bf16; train & gene hi-only (RNE).

#define NG 2500
#define NT 20000
#define NE 640000
#define NCLS 16
#define CAP 96

typedef unsigned short u16;
typedef unsigned int u32;

typedef float f32x4 __attribute__((ext_vector_type(4)));
typedef __bf16 bf16x8 __attribute__((ext_vector_type(8)));

__device__ __forceinline__ float b2f(u16 u) { return __uint_as_float(((u32)u) << 16); }
__device__ __forceinline__ float blo(u32 p) { return __uint_as_float(p << 16); }
__device__ __forceinline__ float bhi(u32 p) { return __uint_as_float(p & 0xffff0000u); }
__device__ __forceinline__ u16 f2b(float f) {  // RNE fp32->bf16
    u32 u = __float_as_uint(f);
    return (u16)((u + 0x7fffu + ((u >> 16) & 1u)) >> 16);
}

// ---- sizes ---------------------------------------------------------------
#define B1N 81920   // K=640: train k 0..499, zero 500..511, agg 512..639; N=128
#define B2N 32768   // K=256: h1 (W2s) 0..127, agg (W2n) 128..255; N=128
#define B3N 16384   // K=128 Wc1, N=128
#define B4N 2048    // K=128 Wc2, N=16
#define NEB 313     // edge blocks (8 edges/thread)
#define GNB 625     // gene-convert blocks
#define PKB 520     // pack blocks

// ---- fused prep -----------------------------------------------------------
__global__ __launch_bounds__(256) void k_prep(
    const int* __restrict__ esrc, const int* __restrict__ edst,
    int* __restrict__ cnt, u16* __restrict__ csr,
    const float* __restrict__ gene, u32* __restrict__ GH32,
    const float* __restrict__ W1n, const float* __restrict__ W1s,
    const float* __restrict__ W2n, const float* __restrict__ W2s,
    const float* __restrict__ Wc1, const float* __restrict__ Wc2,
    u16* __restrict__ B1h, u16* __restrict__ B1l,
    u16* __restrict__ B2h, u16* __restrict__ B2l,
    u16* __restrict__ B3h, u16* __restrict__ B3l,
    u16* __restrict__ B4h, u16* __restrict__ B4l) {
    int blk = blockIdx.x, t = threadIdx.x;
    if (blk < NEB) {
        int e0 = (blk * 256 + t) * 8;
        if (e0 < NE) {                      // NE % 8 == 0 -> all-or-nothing
            int4 sA = *(const int4*)(esrc + e0);
            int4 sB = *(const int4*)(esrc + e0 + 4);
            int4 dA = *(const int4*)(edst + e0);
            int4 dB = *(const int4*)(edst + e0 + 4);
            int ss[8] = {sA.x, sA.y, sA.z, sA.w, sB.x, sB.y, sB.z, sB.w};
            int dd[8] = {dA.x, dA.y, dA.z, dA.w, dB.x, dB.y, dB.z, dB.w};
#pragma unroll
            for (int i = 0; i < 8; ++i) {   // 8 independent atomic chains
                unsigned d = (unsigned)dd[i];
                if (d < NT) {
                    int slot = atomicAdd(&cnt[d], 1);
                    if (slot < CAP) csr[(size_t)d * CAP + slot] = (u16)ss[i];
                }
            }
        }
        return;
    }
    if (blk < NEB + GNB) {
        int idx = (blk - NEB) * 256 + t;  // < 160000
        float2 v = ((const float2*)gene)[idx];
        GH32[idx] = (u32)f2b(v.x) | ((u32)f2b(v.y) << 16);
        return;
    }
    // ---- weight pack (split hi/lo, B-fragment order) ----
    int idx = (blk - NEB - GNB) * 256 + t;
    float v = 0.f;
    u16 *ph = 0, *pl = 0;
    int off = 0;
    if (idx < B1N) {
        int j = idx & 7, l = (idx >> 3) & 63, rest = idx >> 9;
        int g = rest & 7, kk = rest >> 3;
        int k = kk * 32 + ((l >> 4) << 3) + j, n = (g << 4) + (l & 15);
        if (k < 500) v = W1s[k * 128 + n];
        else if (k >= 512) v = W1n[(k - 512) * 128 + n];
        ph = B1h; pl = B1l; off = idx;
    } else if (idx < B1N + B2N) {
        int e = idx - B1N;
        int j = e & 7, l = (e >> 3) & 63, rest = e >> 9;
        int g = rest & 7, kk = rest >> 3;
        int k = kk * 32 + ((l >> 4) << 3) + j, n = (g << 4) + (l & 15);
        v = (k < 128) ? W2s[k * 128 + n] : W2n[(k - 128) * 128 + n];
        ph = B2h; pl = B2l; off = e;
    } else if (idx < B1N + B2N + B3N) {
        int e = idx - (B1N + B2N);
        int j = e & 7, l = (e >> 3) & 63, rest = e >> 9;
        int g = rest & 7, kk = rest >> 3;
        int k = kk * 32 + ((l >> 4) << 3) + j, n = (g << 4) + (l & 15);
        v = Wc1[k * 128 + n];
        ph = B3h; pl = B3l; off = e;
    } else if (idx < B1N + B2N + B3N + B4N) {
        int e = idx - (B1N + B2N + B3N);
        int j = e & 7, l = (e >> 3) & 63, kk = e >> 9;
        int k = kk * 32 + ((l >> 4) << 3) + j, n = l & 15;
        v = Wc2[k * 16 + n];
        ph = B4h; pl = B4l; off = e;
    }
    if (ph) {
        u16 hi = f2b(v);
        u16 lo = f2b(v - b2f(hi));
        ph[off] = hi;
        pl[off] = lo;
    }
}

// ---- fused gather + stage + 4-layer MFMA ----------------------------------
// Block: 512 thr (8 waves), 32 rows (2 tiles). wave = col-group g (0..7);
// each wave handles BOTH row-tiles (acc0/acc1) -> B bytes read once/block.
// Shared pool (u16 units):
//   SAGh @0      [32*136]    SAGl @4352  [32*136]
//   S1h  @8704   [32*136]    S1l  @13056 [32*136]
//   S2h  @17408  [32*136]    S2l  @21760 [32*136]
//   TS   @8704   [32*520]  (train tile bf16, overlays S1h..S2l; dead after
//                           layer1 kk0..15 -> barrier before S1 epilogue)
__global__ __launch_bounds__(512) void k_mega(
    const int* __restrict__ cnt, const u16* __restrict__ csr,
    const u16* __restrict__ GH, const float* __restrict__ train,
    const u16* __restrict__ B1h, const u16* __restrict__ B1l,
    const u16* __restrict__ B2h, const u16* __restrict__ B2l,
    const u16* __restrict__ B3h, const u16* __restrict__ B3l,
    const u16* __restrict__ B4h, const u16* __restrict__ B4l,
    const float* __restrict__ b1, const float* __restrict__ b2,
    const float* __restrict__ bc1, const float* __restrict__ bc2,
    float* __restrict__ out) {
    __shared__ __align__(16) u16 SMEM[26112];   // 52224 B
    u16* SAGh = SMEM;
    u16* SAGl = SMEM + 4352;
    u16* S1h = SMEM + 8704;
    u16* S1l = SMEM + 13056;
    u16* S2h = SMEM + 17408;
    u16* S2l = SMEM + 21760;
    u16* TS = SMEM + 8704;                      // overlays S1h..S2l

    int t = threadIdx.x;
    int row0 = blockIdx.x * 32;

    // ---- phase 0a: issue train-tile loads (latency hides under gather) ----
    float4 st[8];
    {
        const float4* tb = (const float4*)(train + (size_t)row0 * 500);
#pragma unroll
        for (int i = 0; i < 7; ++i) st[i] = tb[t + i * 512];
        if (t < 416) st[7] = tb[t + 3584];      // 4000 float4 = 32 rows x 125
    }

    // ---- phase 0b: gather-mean of gene-hi into SAG (batched indices) ----
    {
        int r = t >> 4, cg = t & 15;           // row 0..31, col-group 0..15
        int d = row0 + r;
        int ctrue = cnt[d];
        int c = ctrue > CAP ? CAP : ctrue;
        const u16* crow = csr + (size_t)d * CAP;
        float a[8];
#pragma unroll
        for (int p = 0; p < 8; ++p) a[p] = 0.f;

#define GHL(s) (*(const uint4*)(GH + (size_t)(s) * 128 + cg * 8))
#define ACC(p)                                   \
        do {                                     \
            a[0] += blo((p).x); a[1] += bhi((p).x); \
            a[2] += blo((p).y); a[3] += bhi((p).y); \
            a[4] += blo((p).z); a[5] += bhi((p).z); \
            a[6] += blo((p).w); a[7] += bhi((p).w); \
        } while (0)

        int j = 0;
        for (; j + 8 <= c; j += 8) {           // 1 idx load -> 8 row loads
            uint4 i4 = *(const uint4*)(crow + j);
            int s0 = i4.x & 0xffff, s1 = i4.x >> 16;
            int s2 = i4.y & 0xffff, s3 = i4.y >> 16;
            int s4 = i4.z & 0xffff, s5 = i4.z >> 16;
            int s6 = i4.w & 0xffff, s7 = i4.w >> 16;
            uint4 p0 = GHL(s0); uint4 p1 = GHL(s1);
            uint4 p2 = GHL(s2); uint4 p3 = GHL(s3);
            ACC(p0); ACC(p1); ACC(p2); ACC(p3);
            uint4 p4 = GHL(s4); uint4 p5 = GHL(s5);
            uint4 p6 = GHL(s6); uint4 p7 = GHL(s7);
            ACC(p4); ACC(p5); ACC(p6); ACC(p7);
        }
        if (j < c) {                            // clamped predicated tail batch
            uint4 i4 = *(const uint4*)(crow + j);  // j<=88 -> slots j..j+7 <96
            u32 w[4] = {i4.x, i4.y, i4.z, i4.w};
#pragma unroll
            for (int k = 0; k < 8; ++k) {
                int s = (int)((w[k >> 1] >> ((k & 1) * 16)) & 0xffffu);
                bool live = (j + k) < c;
                s = live ? s : 0;               // garbage slots never derefed
                uint4 p = GHL(s);
                if (live) ACC(p);
            }
        }
#undef GHL
#undef ACC

        float inv = (ctrue > 0) ? 1.f / (float)ctrue : 0.f;
        int base = (r * 136 + cg * 8) >> 1;    // u32 index (even)
        u32* SH = (u32*)SAGh;
        u32* SL = (u32*)SAGl;
#pragma unroll
        for (int p = 0; p < 4; ++p) {
            float x = a[2 * p] * inv, y = a[2 * p + 1] * inv;
            u16 hx = f2b(x), hy = f2b(y);
            SH[base + p] = (u32)hx | ((u32)hy << 16);
            SL[base + p] = (u32)f2b(x - b2f(hx)) | ((u32)f2b(y - b2f(hy)) << 16);
        }
    }

    // ---- phase 0c: convert staged tile -> TS (row-major [32][520] bf16) ----
    {
        u32* T32 = (u32*)TS;
#pragma unroll
        for (int i = 0; i < 8; ++i) {
            int idx = t + i * 512;
            if (i == 7 && t >= 416) break;
            int r = idx / 125, c4 = idx - r * 125;
            int base = r * 260 + c4 * 2;       // u32 units; row stride 520 u16
            T32[base] = (u32)f2b(st[i].x) | ((u32)f2b(st[i].y) << 16);
            T32[base + 1] = (u32)f2b(st[i].z) | ((u32)f2b(st[i].w) << 16);
        }
        if (t < 192) {                          // zero cols 500..511
            int r = t / 6, c = t - r * 6;
            T32[r * 260 + 250 + c] = 0;
        }
    }
    __syncthreads();

    int lane = t & 63, g = t >> 6;  // wave index = col-group 0..7
    int m = lane & 15, q = lane >> 4, n16 = lane & 15;

    int hr0 = m * 136 + q * 8;
    int hr1 = (16 + m) * 136 + q * 8;
    int cr0 = q * 4, cr1 = 16 + q * 4;
    const f32x4 z4 = {0.f, 0.f, 0.f, 0.f};
    f32x4 acc0 = z4, acc1 = z4;

    // ---- layer1: K=640 (train bf16 kk0..15 from TS; agg kk16..19 SAG) ----
    const u16* tA0 = TS + m * 520 + q * 8;
    const u16* tA1 = TS + (16 + m) * 520 + q * 8;
#pragma unroll
    for (int kk = 0; kk < 16; ++kk) {
        bf16x8 a0 = *(const bf16x8*)(tA0 + kk * 32);
        bf16x8 a1 = *(const bf16x8*)(tA1 + kk * 32);
        size_t bo = ((size_t)(kk * 8 + g) * 64 + lane) * 8;
        bf16x8 bh = *(const bf16x8*)(B1h + bo);
        bf16x8 bl = *(const bf16x8*)(B1l + bo);
        acc0 = __builtin_amdgcn_mfma_f32_16x16x32_bf16(a0, bh, acc0, 0, 0, 0);
        acc0 = __builtin_amdgcn_mfma_f32_16x16x32_bf16(a0, bl, acc0, 0, 0, 0);
        acc1 = __builtin_amdgcn_mfma_f32_16x16x32_bf16(a1, bh, acc1, 0, 0, 0);
        acc1 = __builtin_amdgcn_mfma_f32_16x16x32_bf16(a1, bl, acc1, 0, 0, 0);
    }
#pragma unroll
    for (int kk = 16; kk < 20; ++kk) {
        int o = (kk - 16) * 32;
        bf16x8 ah0 = *(const bf16x8*)(SAGh + hr0 + o);
        bf16x8 al0 = *(const bf16x8*)(SAGl + hr0 + o);
        bf16x8 ah1 = *(const bf16x8*)(SAGh + hr1 + o);
        bf16x8 al1 = *(const bf16x8*)(SAGl + hr1 + o);
        size_t bo = ((size_t)(kk * 8 + g) * 64 + lane) * 8;
        bf16x8 bh = *(const bf16x8*)(B1h + bo);
        bf16x8 bl = *(const bf16x8*)(B1l + bo);
        acc0 = __builtin_amdgcn_mfma_f32_16x16x32_bf16(ah0, bh, acc0, 0, 0, 0);
        acc0 = __builtin_amdgcn_mfma_f32_16x16x32_bf16(ah0, bl, acc0, 0, 0, 0);
        acc0 = __builtin_amdgcn_mfma_f32_16x16x32_bf16(al0, bh, acc0, 0, 0, 0);
        acc1 = __builtin_amdgcn_mfma_f32_16x16x32_bf16(ah1, bh, acc1, 0, 0, 0);
        acc1 = __builtin_amdgcn_mfma_f32_16x16x32_bf16(ah1, bl, acc1, 0, 0, 0);
        acc1 = __builtin_amdgcn_mfma_f32_16x16x32_bf16(al1, bh, acc1, 0, 0, 0);
    }
    __syncthreads();   // TS (overlaid on S1/S2) dead only when ALL waves passed
    {
        int n = g * 16 + n16;
        float bias = b1[n];
#pragma unroll
        for (int rg = 0; rg < 4; ++rg) {
            float v0 = acc0[rg] + bias; v0 = v0 > 0.f ? v0 : 0.f;
            float v1 = acc1[rg] + bias; v1 = v1 > 0.f ? v1 : 0.f;
            u16 h0 = f2b(v0), h1v = f2b(v1);
            S1h[(cr0 + rg) * 136 + n] = h0; S1l[(cr0 + rg) * 136 + n] = f2b(v0 - b2f(h0));
            S1h[(cr1 + rg) * 136 + n] = h1v; S1l[(cr1 + rg) * 136 + n] = f2b(v1 - b2f(h1v));
        }
    }
    __syncthreads();

    // ---- layer2: K=256 (h1 kk0..3 S1; agg kk4..7 SAG) ----
    acc0 = z4; acc1 = z4;
#pragma unroll
    for (int kk = 0; kk < 8; ++kk) {
        const u16* Ph = (kk < 4) ? S1h : SAGh;
        const u16* Pl = (kk < 4) ? S1l : SAGl;
        int o = (kk & 3) * 32;
        bf16x8 ah0 = *(const bf16x8*)(Ph + hr0 + o);
        bf16x8 al0 = *(const bf16x8*)(Pl + hr0 + o);
        bf16x8 ah1 = *(const bf16x8*)(Ph + hr1 + o);
        bf16x8 al1 = *(const bf16x8*)(Pl + hr1 + o);
        size_t bo = ((size_t)(kk * 8 + g) * 64 + lane) * 8;
        bf16x8 bh = *(const bf16x8*)(B2h + bo);
        bf16x8 bl = *(const bf16x8*)(B2l + bo);
        acc0 = __builtin_amdgcn_mfma_f32_16x16x32_bf16(ah0, bh, acc0, 0, 0, 0);
        acc0 = __builtin_amdgcn_mfma_f32_16x16x32_bf16(ah0, bl, acc0, 0, 0, 0);
        acc0 = __builtin_amdgcn_mfma_f32_16x16x32_bf16(al0, bh, acc0, 0, 0, 0);
        acc1 = __builtin_amdgcn_mfma_f32_16x16x32_bf16(ah1, bh, acc1, 0, 0, 0);
        acc1 = __builtin_amdgcn_mfma_f32_16x16x32_bf16(ah1, bl, acc1, 0, 0, 0);
        acc1 = __builtin_amdgcn_mfma_f32_16x16x32_bf16(al1, bh, acc1, 0, 0, 0);
    }
    {
        int n = g * 16 + n16;
        float bias = b2[n];
#pragma unroll
        for (int rg = 0; rg < 4; ++rg) {
            float v0 = acc0[rg] + bias; v0 = v0 > 0.f ? v0 : 0.f;
            float v1 = acc1[rg] + bias; v1 = v1 > 0.f ? v1 : 0.f;
            u16 h0 = f2b(v0), h1v = f2b(v1);
            S2h[(cr0 + rg) * 136 + n] = h0; S2l[(cr0 + rg) * 136 + n] = f2b(v0 - b2f(h0));
            S2h[(cr1 + rg) * 136 + n] = h1v; S2l[(cr1 + rg) * 136 + n] = f2b(v1 - b2f(h1v));
        }
    }
    __syncthreads();

    // ---- layer3: K=128 (h2 S2) -> S1 ----
    acc0 = z4; acc1 = z4;
#pragma unroll
    for (int kk = 0; kk < 4; ++kk) {
        int o = kk * 32;
        bf16x8 ah0 = *(const bf16x8*)(S2h + hr0 + o);
        bf16x8 al0 = *(const bf16x8*)(S2l + hr0 + o);
        bf16x8 ah1 = *(const bf16x8*)(S2h + hr1 + o);
        bf16x8 al1 = *(const bf16x8*)(S2l + hr1 + o);
        size_t bo = ((size_t)(kk * 8 + g) * 64 + lane) * 8;
        bf16x8 bh = *(const bf16x8*)(B3h + bo);
        bf16x8 bl = *(const bf16x8*)(B3l + bo);
        acc0 = __builtin_amdgcn_mfma_f32_16x16x32_bf16(ah0, bh, acc0, 0, 0, 0);
        acc0 = __builtin_amdgcn_mfma_f32_16x16x32_bf16(ah0, bl, acc0, 0, 0, 0);
        acc0 = __builtin_amdgcn_mfma_f32_16x16x32_bf16(al0, bh, acc0, 0, 0, 0);
        acc1 = __builtin_amdgcn_mfma_f32_16x16x32_bf16(ah1, bh, acc1, 0, 0, 0);
        acc1 = __builtin_amdgcn_mfma_f32_16x16x32_bf16(ah1, bl, acc1, 0, 0, 0);
        acc1 = __builtin_amdgcn_mfma_f32_16x16x32_bf16(al1, bh, acc1, 0, 0, 0);
    }
    {
        int n = g * 16 + n16;
        float bias = bc1[n];
#pragma unroll
        for (int rg = 0; rg < 4; ++rg) {
            float v0 = acc0[rg] + bias; v0 = v0 > 0.f ? v0 : 0.f;
            float v1 = acc1[rg] + bias; v1 = v1 > 0.f ? v1 : 0.f;
            u16 h0 = f2b(v0), h1v = f2b(v1);
            S1h[(cr0 + rg) * 136 + n] = h0; S1l[(cr0 + rg) * 136 + n] = f2b(v0 - b2f(h0));
            S1h[(cr1 + rg) * 136 + n] = h1v; S1l[(cr1 + rg) * 136 + n] = f2b(v1 - b2f(h1v));
        }
    }
    __syncthreads();

    // ---- layer4: K=128, N=16 (waves 0,1 = tiles 0,1) ----
    if (g < 2) {
        int hr = (g == 0) ? hr0 : hr1;
        int cr = (g == 0) ? cr0 : cr1;
        f32x4 a4 = z4;
#pragma unroll
        for (int kk = 0; kk < 4; ++kk) {
            bf16x8 ah = *(const bf16x8*)(S1h + hr + kk * 32);
            bf16x8 al = *(const bf16x8*)(S1l + hr + kk * 32);
            size_t bo = ((size_t)kk * 64 + lane) * 8;
            bf16x8 bh = *(const bf16x8*)(B4h + bo);
            bf16x8 bl = *(const bf16x8*)(B4l + bo);
            a4 = __builtin_amdgcn_mfma_f32_16x16x32_bf16(ah, bh, a4, 0, 0, 0);
            a4 = __builtin_amdgcn_mfma_f32_16x16x32_bf16(ah, bl, a4, 0, 0, 0);
            a4 = __builtin_amdgcn_mfma_f32_16x16x32_bf16(al, bh, a4, 0, 0, 0);
        }
        float bias = bc2[n16];
#pragma unroll
        for (int rg = 0; rg < 4; ++rg)
            out[(size_t)(row0 + cr + rg) * NCLS + n16] = a4[rg] + bias;
    }
}

extern "C" void kernel_launch(void* const* d_in, const int* in_sizes, int n_in,
                              void* d_out, int out_size, void* d_ws, size_t ws_size,
                              hipStream_t stream) {
    const float* gene = (const float*)d_in[0];
    const float* train = (const float*)d_in[1];
    const int* esrc = (const int*)d_in[2];
    const int* edst = (const int*)d_in[3];

    char* ws = (char*)d_ws;
    int* cnt = (int*)(ws + 0);              //    80000
    u16* csr = (u16*)(ws + 80000);          //  3840000
    u16* GH = (u16*)(ws + 3920000);         //   640000 (2500*128 u16)
    u16* B1h = (u16*)(ws + 4560000);        //   163840
    u16* B1l = (u16*)(ws + 4723840);        //   163840
    u16* B2h = (u16*)(ws + 4887680);        //    65536
    u16* B2l = (u16*)(ws + 4953216);        //    65536
    u16* B3h = (u16*)(ws + 5018752);        //    32768
    u16* B3l = (u16*)(ws + 5051520);        //    32768
    u16* B4h = (u16*)(ws + 5084288);        //     4096
    u16* B4l = (u16*)(ws + 5088384);        //     4096
    // total 5,092,480 B

    hipMemsetAsync(cnt, 0, NT * sizeof(int), stream);
    k_prep<<<NEB + GNB + PKB, 256, 0, stream>>>(
        esrc, edst, cnt, csr, gene, (u32*)GH,
        (const float*)d_in[4], (const float*)d_in[5], (const float*)d_in[7],
        (const float*)d_in[8], (const float*)d_in[10], (const float*)d_in[12],
        B1h, B1l, B2h, B2l, B3h, B3l, B4h, B4l);
    k_mega<<<NT / 32, 512, 0, stream>>>(
        cnt, csr, GH, train, B1h, B1l, B2h, B2l, B3h, B3l, B4h, B4l,
        (const float*)d_in[6], (const float*)d_in[9], (const float*)d_in[11],
        (const float*)d_in[13], (float*)d_out);
}